// Round 21
// baseline (57.973 us; speedup 1.0000x reference)
//
#include <hip/hip_runtime.h>
#include <hip/hip_bf16.h>

// Linear attention, fp32. N=8, L=S=8192, H=8, D=Dv=32.
// out[n,l,h,v] = (sum_d phiQ[l,d]*KV[d][v]) * 1/(sum_d phiQ[l,d]*Ksum[d] + 1e-6)
// where KV[d][v] = sum_s phiK[s,d]*values[s,v]  (the /S and *S of the reference
// cancel exactly: S is a power of two).
//
// R21 = R20 with the compile fix: __builtin_nontemporal_store requires a
// clang vector type, not HIP's struct float4 -> store f32x4 via f32x4*.
// Design (unchanged from R20): TRANSPOSED-D phase2. mfma(KV_frag, phiQ_frag)
// gives lane out[l=row_l][v=kg*4+r] = one dense float4; stores collapse from
// 8 scattered 4B dwords to 2 dense 16B NT stores per thread; z needs no shfl
// broadcast. Phase1 = R14 (MFMA, at floor ~20.7us measured R16).

#define N_      8
#define L_      8192
#define S_      8192
#define H_      8
#define D_      32
#define NH_     64            // N*H
#define CH1_    16            // phase-1 s-chunks per (n,h)
#define SPC1_   512           // s per phase-1 block
#define STR1_   36            // u32 row stride (144B: 16B-aligned, shift 4)
#define KVE_    (D_ * D_)     // 1024
#define PKS_    (KVE_ + D_)   // 1056 floats: KV + Ksum

typedef short short8 __attribute__((ext_vector_type(8)));
typedef float f32x4  __attribute__((ext_vector_type(4)));

__device__ __forceinline__ float phi_f(float x) {
    // elu(x)+1 : x>0 -> x+1 ; else exp(x)
    return x > 0.f ? x + 1.f : __expf(x);
}

__device__ __forceinline__ unsigned short bf16_bits(float x) {
    __hip_bfloat16 h = __float2bfloat16(x);   // RNE
    unsigned short u;
    __builtin_memcpy(&u, &h, 2);
    return u;
}

__device__ __forceinline__ void split_bf16(float x, short& hi, short& lo) {
    __hip_bfloat16 hb = __float2bfloat16(x);        // RNE
    const float xh = __bfloat162float(hb);
    __hip_bfloat16 lb = __float2bfloat16(x - xh);
    __builtin_memcpy(&hi, &hb, 2);
    __builtin_memcpy(&lo, &lb, 2);
}

// ---------------- Phase 1: C[32d x 32v] = phiK^T . V per (n,h,chunk) --------
// (R14 version: MFMA, single-bf16 K/V, exact fp32 Ksum, g^=row>>3 swizzle.)
template <bool ATOMIC>
__global__ __launch_bounds__(256) void la_phase1(
    const float* __restrict__ keys, const float* __restrict__ values,
    float* __restrict__ outp /* ATOMIC ? kvfinal[NH][PKS] : partials[NH][CH1][PKS] */)
{
    __shared__ unsigned kS[2][32][STR1_];
    __shared__ unsigned vS[2][32][STR1_];
    __shared__ float red_ks[4][8][4];
    const int nh = blockIdx.x, chunk = blockIdx.y;
    const int n = nh >> 3, h = nh & 7;
    const int t = threadIdx.x, lane = t & 63, w = t >> 6;
    const int row8 = t >> 3;           // 0..31 (s-row within tile half)
    const int c4   = t & 7;            // float4 column (4 d's / 4 v's)
    const int row_l = lane & 15, kg = lane >> 4;
    const int dt = w >> 1, vt = w & 1; // wave's C-tile
    const int odd = row8 & 1;
    const int dv0 = (c4 << 2) + (odd ? 2 : 0);   // first of 2 owned d-rows
    const int s2lo = row8 >> 1;                  // u32 s-pair index (lo half)
    const float* kb = keys   + ((size_t)n * S_) * 256 + h * 32 + (c4 << 2);
    const float* vb = values + ((size_t)n * S_) * 256 + h * 32 + (c4 << 2);
    const int s0 = chunk * SPC1_;

    float ks4[4] = {0.f, 0.f, 0.f, 0.f};
    f32x4 cacc = {0.f, 0.f, 0.f, 0.f};
    float4 Lka, Lkb, Lva, Lvb;

    auto LOADT = [&](int tb) {
        const size_t g0 = ((size_t)(s0 + (tb << 6) + row8)) << 8;
        const size_t g1 = ((size_t)(s0 + (tb << 6) + row8 + 32)) << 8;
        Lka = *(const float4*)(kb + g0);
        Lkb = *(const float4*)(kb + g1);
        Lva = *(const float4*)(vb + g0);
        Lvb = *(const float4*)(vb + g1);
    };
    auto STORE4 = [&](unsigned (*Sarr)[STR1_], const unsigned short* x, int s2) {
        const unsigned mA = (unsigned)x[0] | ((unsigned)x[1] << 16);
        const unsigned mB = (unsigned)x[2] | ((unsigned)x[3] << 16);
        const unsigned pA = __shfl_xor(mA, 8);
        const unsigned pB = __shfl_xor(mB, 8);
        const unsigned m = odd ? mB : mA, p = odd ? pB : pA;
        const unsigned se = odd ? p : m;          // s-even's two bf16 (j, j+1)
        const unsigned so = odd ? m : p;          // s-odd's
        const unsigned w0 = (se & 0xffffu) | ((so & 0xffffu) << 16);
        const unsigned w1 = (se >> 16) | (so & 0xffff0000u);
        Sarr[dv0][4 * ((s2 >> 2) ^ (dv0 >> 3)) + (s2 & 3)]           = w0;
        Sarr[dv0 + 1][4 * ((s2 >> 2) ^ ((dv0 + 1) >> 3)) + (s2 & 3)] = w1;
    };
    auto PROCT = [&](int buf) {
        const float f0[4] = {phi_f(Lka.x), phi_f(Lka.y), phi_f(Lka.z), phi_f(Lka.w)};
        const float f1[4] = {phi_f(Lkb.x), phi_f(Lkb.y), phi_f(Lkb.z), phi_f(Lkb.w)};
        unsigned short kx[4], ky[4], vx[4], vy[4];
#pragma unroll
        for (int j = 0; j < 4; ++j) ks4[j] += f0[j] + f1[j];
        kx[0] = bf16_bits(f0[0]); kx[1] = bf16_bits(f0[1]);
        kx[2] = bf16_bits(f0[2]); kx[3] = bf16_bits(f0[3]);
        ky[0] = bf16_bits(f1[0]); ky[1] = bf16_bits(f1[1]);
        ky[2] = bf16_bits(f1[2]); ky[3] = bf16_bits(f1[3]);
        vx[0] = bf16_bits(Lva.x); vx[1] = bf16_bits(Lva.y);
        vx[2] = bf16_bits(Lva.z); vx[3] = bf16_bits(Lva.w);
        vy[0] = bf16_bits(Lvb.x); vy[1] = bf16_bits(Lvb.y);
        vy[2] = bf16_bits(Lvb.z); vy[3] = bf16_bits(Lvb.w);
        STORE4(kS[buf], kx, s2lo);
        STORE4(kS[buf], ky, s2lo + 16);
        STORE4(vS[buf], vx, s2lo);
        STORE4(vS[buf], vy, s2lo + 16);
    };
    auto FRAG = [&](const unsigned (*Sarr)[STR1_], int row, int sh) -> short8 {
        const int g = ((sh << 2) | kg) ^ (row >> 3);
        union { uint4 u; short8 s; } U;
        U.u = *(const uint4*)&Sarr[row][g << 2];
        return U.s;
    };
    auto COMPT = [&](int buf) {
#pragma unroll
        for (int sh = 0; sh < 2; ++sh) {
            const short8 A = FRAG(kS[buf], (dt << 4) + row_l, sh);
            const short8 B = FRAG(vS[buf], (vt << 4) + row_l, sh);
            cacc = __builtin_amdgcn_mfma_f32_16x16x32_bf16(A, B, cacc, 0, 0, 0);
        }
    };

    LOADT(0);
    PROCT(0);
    __syncthreads();
#pragma unroll
    for (int tb = 0; tb < 8; ++tb) {
        const int cur = tb & 1;
        if (tb < 7) LOADT(tb + 1);       // next-tile loads in flight (T14)
        COMPT(cur);
        if (tb < 7) PROCT(cur ^ 1);      // waits vmcnt, stages other buffer
        __syncthreads();
    }

    // ksum: butterfly over lane bits 3..5 (8 same-c4 lanes), then cross-wave
#pragma unroll
    for (int j = 0; j < 4; ++j) {
        float x = ks4[j];
        x += __shfl_xor(x, 8);
        x += __shfl_xor(x, 16);
        x += __shfl_xor(x, 32);
        ks4[j] = x;
    }
    if (lane < 8) {
#pragma unroll
        for (int j = 0; j < 4; ++j) red_ks[w][lane][j] = ks4[j];
    }
    __syncthreads();

    if (ATOMIC) {
        float* p = outp + (size_t)nh * PKS_;
#pragma unroll
        for (int r = 0; r < 4; ++r) {
            const int dd = (dt << 4) + (kg << 2) + r;   // D row = (lane>>4)*4+reg
            const int vv = (vt << 4) + row_l;           // D col = lane&15
            atomicAdd(&p[dd * D_ + vv], cacc[r]);
        }
        if (t < 32) {
            const float s = red_ks[0][t >> 2][t & 3] + red_ks[1][t >> 2][t & 3]
                          + red_ks[2][t >> 2][t & 3] + red_ks[3][t >> 2][t & 3];
            atomicAdd(&p[KVE_ + t], s);
        }
    } else {
        float* p = outp + ((size_t)nh * CH1_ + chunk) * PKS_;
#pragma unroll
        for (int r = 0; r < 4; ++r) {
            const int dd = (dt << 4) + (kg << 2) + r;
            const int vv = (vt << 4) + row_l;
            p[dd * D_ + vv] = cacc[r];
        }
        if (t < 32) {
            p[KVE_ + t] = red_ks[0][t >> 2][t & 3] + red_ks[1][t >> 2][t & 3]
                        + red_ks[2][t >> 2][t & 3] + red_ks[3][t >> 2][t & 3];
        }
    }
}

// ---- Phase 1b: deterministic 16-way reduce + split-bf16 transpose ----
__global__ __launch_bounds__(256) void la_reduce(
    const float* __restrict__ partials,
    short* __restrict__ kvThi, short* __restrict__ kvTlo,
    float* __restrict__ ksumf)
{
    const int nh = blockIdx.x;
    for (int e = threadIdx.x; e < PKS_; e += 256) {
        const float* p = partials + (size_t)nh * CH1_ * PKS_ + e;
        float s = 0.f;
#pragma unroll
        for (int c = 0; c < CH1_; ++c) s += p[(size_t)c * PKS_];
        if (e < KVE_) {
            const int d = e >> 5, v = e & 31;
            short hi, lo; split_bf16(s, hi, lo);
            kvThi[nh * KVE_ + v * D_ + d] = hi;
            kvTlo[nh * KVE_ + v * D_ + d] = lo;
        } else {
            ksumf[nh * D_ + (e - KVE_)] = s;
        }
    }
}

// atomic-path variant: same split/transpose from a finished kvf buffer
__global__ __launch_bounds__(256) void la_convert(
    const float* __restrict__ kvf,
    short* __restrict__ kvThi, short* __restrict__ kvTlo,
    float* __restrict__ ksumf)
{
    const int nh = blockIdx.x;
    for (int e = threadIdx.x; e < PKS_; e += 256) {
        const float s = kvf[(size_t)nh * PKS_ + e];
        if (e < KVE_) {
            const int d = e >> 5, v = e & 31;
            short hi, lo; split_bf16(s, hi, lo);
            kvThi[nh * KVE_ + v * D_ + d] = hi;
            kvTlo[nh * KVE_ + v * D_ + d] = lo;
        } else {
            ksumf[nh * D_ + (e - KVE_)] = s;
        }
    }
}

__global__ void la_zero(float* __restrict__ p, int nelem) {
    const int i = blockIdx.x * 256 + threadIdx.x;
    if (i < nelem) p[i] = 0.f;
}

// ------- Phase 2: MFMA split-bf16, transposed D, dense NT f32x4 stores ------
// Block = 512 threads (8 waves) x 16 rows x ALL 8 h; Q staged via LDS (phi
// fused, granule swizzle); wave w computes h=w. MFMA called as
// mfma(KV_frag, phiQ_frag): lane holds out[l=row_l][v=kg*4+r] -> dense
// f32x4; 2 NT f32x4 stores/thread (was 8 scattered dwords).
__global__ __launch_bounds__(512) void la_phase2(
    const float* __restrict__ queries,
    const short* __restrict__ kvThi, const short* __restrict__ kvTlo,
    const float* __restrict__ ksumf, float* __restrict__ out)
{
    __shared__ float qs[16 * 256];              // 16 KB, swizzled granules
    const int t = threadIdx.x, lane = t & 63, w = t >> 6;
    const size_t rowg0 = (size_t)blockIdx.x * 16;
    const int n  = (int)(rowg0 >> 13);
    const int h  = w;                           // wave's head
    const int nh = n * 8 + h;
    const int row_l = lane & 15;                // l-row / KV v-row (frag row)
    const int kg    = lane >> 4;                // k-group: k = kg*8 + e

    // ---- stage 16 rows x 1KB: thread (row = t&15, seg = t>>4) loads 32B ----
    {
        const int row = t & 15, seg = t >> 4;   // seg 0..31
        const float* qp = queries + (rowg0 + row) * 256 + seg * 8;
        const float4 a = *(const float4*)(qp);
        const float4 b = *(const float4*)(qp + 4);
        const int p0 = ((seg << 1) | 0) ^ (row & 7);
        const int p1 = ((seg << 1) | 1) ^ (row & 7);
        *(float4*)&qs[row * 256 + p0 * 4] =
            make_float4(phi_f(a.x), phi_f(a.y), phi_f(a.z), phi_f(a.w));
        *(float4*)&qs[row * 256 + p1 * 4] =
            make_float4(phi_f(b.x), phi_f(b.y), phi_f(b.z), phi_f(b.w));
    }

    // ---- KV + Ksum for this wave's h (L2-hot; issued before the barrier) ----
    const short* bh = kvThi + (size_t)nh * KVE_;
    const short* bl = kvTlo + (size_t)nh * KVE_;
    const short8 bh0 = *(const short8*)(bh + (row_l     ) * D_ + kg * 8);
    const short8 bh1 = *(const short8*)(bh + (row_l + 16) * D_ + kg * 8);
    const short8 bl0 = *(const short8*)(bl + (row_l     ) * D_ + kg * 8);
    const short8 bl1 = *(const short8*)(bl + (row_l + 16) * D_ + kg * 8);
    const float4 kA = *(const float4*)(ksumf + nh * D_ + kg * 8);
    const float4 kB = *(const float4*)(ksumf + nh * D_ + kg * 8 + 4);

    __syncthreads();

    // ---- phiQ[row_l][kg*8..+8] from LDS (granules h*8+kg*2, +1) ----
    float qa[8];
    {
        const int g0 = (h * 8 + kg * 2)     ^ (row_l & 7);
        const int g1 = (h * 8 + kg * 2 + 1) ^ (row_l & 7);
        const float4 f0 = *(const float4*)&qs[row_l * 256 + g0 * 4];
        const float4 f1 = *(const float4*)&qs[row_l * 256 + g1 * 4];
        qa[0] = f0.x; qa[1] = f0.y; qa[2] = f0.z; qa[3] = f0.w;
        qa[4] = f1.x; qa[5] = f1.y; qa[6] = f1.z; qa[7] = f1.w;
    }
    short8 ahi, alo;
#pragma unroll
    for (int e = 0; e < 8; ++e) {
        short hs, ls; split_bf16(qa[e], hs, ls);
        ahi[e] = hs; alo[e] = ls;
    }

    // ---- 6 MFMAs, SWAPPED operands (D = D_old^T): lane -> dense v f32x4 ----
    f32x4 c0 = {0.f, 0.f, 0.f, 0.f}, c1 = {0.f, 0.f, 0.f, 0.f};
    c0 = __builtin_amdgcn_mfma_f32_16x16x32_bf16(bh0, alo, c0, 0, 0, 0);
    c0 = __builtin_amdgcn_mfma_f32_16x16x32_bf16(bl0, ahi, c0, 0, 0, 0);
    c0 = __builtin_amdgcn_mfma_f32_16x16x32_bf16(bh0, ahi, c0, 0, 0, 0);
    c1 = __builtin_amdgcn_mfma_f32_16x16x32_bf16(bh1, alo, c1, 0, 0, 0);
    c1 = __builtin_amdgcn_mfma_f32_16x16x32_bf16(bl1, ahi, c1, 0, 0, 0);
    c1 = __builtin_amdgcn_mfma_f32_16x16x32_bf16(bh1, ahi, c1, 0, 0, 0);

    // ---- dot = phiQ . Ksum in fp32; reduce the 4 k-groups per row ----
    float dt = qa[0] * kA.x;
    dt = fmaf(qa[1], kA.y, dt); dt = fmaf(qa[2], kA.z, dt);
    dt = fmaf(qa[3], kA.w, dt); dt = fmaf(qa[4], kB.x, dt);
    dt = fmaf(qa[5], kB.y, dt); dt = fmaf(qa[6], kB.z, dt);
    dt = fmaf(qa[7], kB.w, dt);
    dt += __shfl_xor(dt, 16);
    dt += __shfl_xor(dt, 32);   // all lanes hold dot[row_l] = own row's dot

    // ---- normalize + dense NT f32x4 stores ----
    const float z = __builtin_amdgcn_rcpf(dt + 1e-6f);
    float* ob = out + (rowg0 + row_l) * 256 + h * D_;
    const f32x4 o0 = {c0[0] * z, c0[1] * z, c0[2] * z, c0[3] * z};
    const f32x4 o1 = {c1[0] * z, c1[1] * z, c1[2] * z, c1[3] * z};
    __builtin_nontemporal_store(o0, (f32x4*)(ob + kg * 4));
    __builtin_nontemporal_store(o1, (f32x4*)(ob + 16 + kg * 4));
}

extern "C" void kernel_launch(void* const* d_in, const int* in_sizes, int n_in,
                              void* d_out, int out_size, void* d_ws, size_t ws_size,
                              hipStream_t stream)
{
    const float* queries = (const float*)d_in[0];
    const float* keys    = (const float*)d_in[1];
    const float* values  = (const float*)d_in[2];
    float* out = (float*)d_out;
    float* ws  = (float*)d_ws;

    const size_t partial_elems = (size_t)NH_ * CH1_ * PKS_;    // 1,081,344 floats
    const size_t split_elems   = (size_t)NH_ * KVE_;           // per hi/lo, in shorts
    const size_t split_floats  = split_elems / 2;              // 32,768 float-slots each
    const size_t ksum_floats   = (size_t)NH_ * D_;             // 2,048
    const dim3 blk(256);
    const dim3 blk2(512);
    const int p2_blocks = (N_ * L_) / 16;                      // 4096

    if (ws_size >= (partial_elems + 2 * split_floats + ksum_floats) * sizeof(float)) {
        // deterministic two-stage reduction + split-bf16 conversion
        float* partials = ws;
        short* kvThi = (short*)(ws + partial_elems);
        short* kvTlo = kvThi + split_elems;
        float* ksumf = (float*)(kvTlo + split_elems);
        la_phase1<false><<<dim3(NH_, CH1_), blk, 0, stream>>>(keys, values, partials);
        la_reduce<<<dim3(NH_), blk, 0, stream>>>(partials, kvThi, kvTlo, ksumf);
        la_phase2<<<dim3(p2_blocks), blk2, 0, stream>>>(queries, kvThi, kvTlo, ksumf, out);
    } else {
        // fallback: atomic accumulation into zeroed kvf, then convert
        float* kvf = ws;
        short* kvThi = (short*)(ws + (size_t)NH_ * PKS_);
        short* kvTlo = kvThi + split_elems;
        float* ksumf = (float*)(kvTlo + split_elems);
        const int nz = (int)((size_t)NH_ * PKS_);
        la_zero<<<dim3((nz + 255) / 256), blk, 0, stream>>>(kvf, nz);
        la_phase1<true><<<dim3(NH_, CH1_), blk, 0, stream>>>(keys, values, kvf);
        la_convert<<<dim3(NH_), blk, 0, stream>>>(kvf, kvThi, kvTlo, ksumf);
        la_phase2<<<dim3(p2_blocks), blk2, 0, stream>>>(queries, kvThi, kvTlo, ksumf, out);
    }
}

// Round 22
// 57.362 us; speedup vs baseline: 1.0107x; 1.0107x over previous
//
#include <hip/hip_runtime.h>
#include <hip/hip_bf16.h>

// Linear attention, fp32. N=8, L=S=8192, H=8, D=Dv=32.
// out[n,l,h,v] = (sum_d phiQ[l,d]*KV[d][v]) * 1/(sum_d phiQ[l,d]*Ksum[d] + 1e-6)
// where KV[d][v] = sum_s phiK[s,d]*values[s,v]  (the /S and *S of the reference
// cancel exactly: S is a power of two).
//
// R22: phase2 2-tiles-per-wave (untested combo of R17's amortization with
// R18's dense LDS staging and R19's NT stores). p2 pinned at ~35us across all
// store/read variants; duty-cycle model says waves are ~1.7x oversubscribed
// only -- doubling per-wave work (all Q loads pre-barrier, B/Ksum amortized
// x2, store tail halved) raises it to ~2.8. Block = 512 thr x 32 rows x 8 h;
// LDS 32KB (4 blocks/CU -> occupancy unchanged). Phase1 = R14 (at floor).

#define N_      8
#define L_      8192
#define S_      8192
#define H_      8
#define D_      32
#define NH_     64            // N*H
#define CH1_    16            // phase-1 s-chunks per (n,h)
#define SPC1_   512           // s per phase-1 block
#define STR1_   36            // u32 row stride (144B: 16B-aligned, shift 4)
#define KVE_    (D_ * D_)     // 1024
#define PKS_    (KVE_ + D_)   // 1056 floats: KV + Ksum

typedef short short8 __attribute__((ext_vector_type(8)));
typedef float f32x4  __attribute__((ext_vector_type(4)));

__device__ __forceinline__ float phi_f(float x) {
    // elu(x)+1 : x>0 -> x+1 ; else exp(x)
    return x > 0.f ? x + 1.f : __expf(x);
}

__device__ __forceinline__ unsigned short bf16_bits(float x) {
    __hip_bfloat16 h = __float2bfloat16(x);   // RNE
    unsigned short u;
    __builtin_memcpy(&u, &h, 2);
    return u;
}

__device__ __forceinline__ void split_bf16(float x, short& hi, short& lo) {
    __hip_bfloat16 hb = __float2bfloat16(x);        // RNE
    const float xh = __bfloat162float(hb);
    __hip_bfloat16 lb = __float2bfloat16(x - xh);
    __builtin_memcpy(&hi, &hb, 2);
    __builtin_memcpy(&lo, &lb, 2);
}

// ---------------- Phase 1: C[32d x 32v] = phiK^T . V per (n,h,chunk) --------
// (R14 version: MFMA, single-bf16 K/V, exact fp32 Ksum, g^=row>>3 swizzle.)
template <bool ATOMIC>
__global__ __launch_bounds__(256) void la_phase1(
    const float* __restrict__ keys, const float* __restrict__ values,
    float* __restrict__ outp /* ATOMIC ? kvfinal[NH][PKS] : partials[NH][CH1][PKS] */)
{
    __shared__ unsigned kS[2][32][STR1_];
    __shared__ unsigned vS[2][32][STR1_];
    __shared__ float red_ks[4][8][4];
    const int nh = blockIdx.x, chunk = blockIdx.y;
    const int n = nh >> 3, h = nh & 7;
    const int t = threadIdx.x, lane = t & 63, w = t >> 6;
    const int row8 = t >> 3;           // 0..31 (s-row within tile half)
    const int c4   = t & 7;            // float4 column (4 d's / 4 v's)
    const int row_l = lane & 15, kg = lane >> 4;
    const int dt = w >> 1, vt = w & 1; // wave's C-tile
    const int odd = row8 & 1;
    const int dv0 = (c4 << 2) + (odd ? 2 : 0);   // first of 2 owned d-rows
    const int s2lo = row8 >> 1;                  // u32 s-pair index (lo half)
    const float* kb = keys   + ((size_t)n * S_) * 256 + h * 32 + (c4 << 2);
    const float* vb = values + ((size_t)n * S_) * 256 + h * 32 + (c4 << 2);
    const int s0 = chunk * SPC1_;

    float ks4[4] = {0.f, 0.f, 0.f, 0.f};
    f32x4 cacc = {0.f, 0.f, 0.f, 0.f};
    float4 Lka, Lkb, Lva, Lvb;

    auto LOADT = [&](int tb) {
        const size_t g0 = ((size_t)(s0 + (tb << 6) + row8)) << 8;
        const size_t g1 = ((size_t)(s0 + (tb << 6) + row8 + 32)) << 8;
        Lka = *(const float4*)(kb + g0);
        Lkb = *(const float4*)(kb + g1);
        Lva = *(const float4*)(vb + g0);
        Lvb = *(const float4*)(vb + g1);
    };
    auto STORE4 = [&](unsigned (*Sarr)[STR1_], const unsigned short* x, int s2) {
        const unsigned mA = (unsigned)x[0] | ((unsigned)x[1] << 16);
        const unsigned mB = (unsigned)x[2] | ((unsigned)x[3] << 16);
        const unsigned pA = __shfl_xor(mA, 8);
        const unsigned pB = __shfl_xor(mB, 8);
        const unsigned m = odd ? mB : mA, p = odd ? pB : pA;
        const unsigned se = odd ? p : m;          // s-even's two bf16 (j, j+1)
        const unsigned so = odd ? m : p;          // s-odd's
        const unsigned w0 = (se & 0xffffu) | ((so & 0xffffu) << 16);
        const unsigned w1 = (se >> 16) | (so & 0xffff0000u);
        Sarr[dv0][4 * ((s2 >> 2) ^ (dv0 >> 3)) + (s2 & 3)]           = w0;
        Sarr[dv0 + 1][4 * ((s2 >> 2) ^ ((dv0 + 1) >> 3)) + (s2 & 3)] = w1;
    };
    auto PROCT = [&](int buf) {
        const float f0[4] = {phi_f(Lka.x), phi_f(Lka.y), phi_f(Lka.z), phi_f(Lka.w)};
        const float f1[4] = {phi_f(Lkb.x), phi_f(Lkb.y), phi_f(Lkb.z), phi_f(Lkb.w)};
        unsigned short kx[4], ky[4], vx[4], vy[4];
#pragma unroll
        for (int j = 0; j < 4; ++j) ks4[j] += f0[j] + f1[j];
        kx[0] = bf16_bits(f0[0]); kx[1] = bf16_bits(f0[1]);
        kx[2] = bf16_bits(f0[2]); kx[3] = bf16_bits(f0[3]);
        ky[0] = bf16_bits(f1[0]); ky[1] = bf16_bits(f1[1]);
        ky[2] = bf16_bits(f1[2]); ky[3] = bf16_bits(f1[3]);
        vx[0] = bf16_bits(Lva.x); vx[1] = bf16_bits(Lva.y);
        vx[2] = bf16_bits(Lva.z); vx[3] = bf16_bits(Lva.w);
        vy[0] = bf16_bits(Lvb.x); vy[1] = bf16_bits(Lvb.y);
        vy[2] = bf16_bits(Lvb.z); vy[3] = bf16_bits(Lvb.w);
        STORE4(kS[buf], kx, s2lo);
        STORE4(kS[buf], ky, s2lo + 16);
        STORE4(vS[buf], vx, s2lo);
        STORE4(vS[buf], vy, s2lo + 16);
    };
    auto FRAG = [&](const unsigned (*Sarr)[STR1_], int row, int sh) -> short8 {
        const int g = ((sh << 2) | kg) ^ (row >> 3);
        union { uint4 u; short8 s; } U;
        U.u = *(const uint4*)&Sarr[row][g << 2];
        return U.s;
    };
    auto COMPT = [&](int buf) {
#pragma unroll
        for (int sh = 0; sh < 2; ++sh) {
            const short8 A = FRAG(kS[buf], (dt << 4) + row_l, sh);
            const short8 B = FRAG(vS[buf], (vt << 4) + row_l, sh);
            cacc = __builtin_amdgcn_mfma_f32_16x16x32_bf16(A, B, cacc, 0, 0, 0);
        }
    };

    LOADT(0);
    PROCT(0);
    __syncthreads();
#pragma unroll
    for (int tb = 0; tb < 8; ++tb) {
        const int cur = tb & 1;
        if (tb < 7) LOADT(tb + 1);       // next-tile loads in flight (T14)
        COMPT(cur);
        if (tb < 7) PROCT(cur ^ 1);      // waits vmcnt, stages other buffer
        __syncthreads();
    }

    // ksum: butterfly over lane bits 3..5 (8 same-c4 lanes), then cross-wave
#pragma unroll
    for (int j = 0; j < 4; ++j) {
        float x = ks4[j];
        x += __shfl_xor(x, 8);
        x += __shfl_xor(x, 16);
        x += __shfl_xor(x, 32);
        ks4[j] = x;
    }
    if (lane < 8) {
#pragma unroll
        for (int j = 0; j < 4; ++j) red_ks[w][lane][j] = ks4[j];
    }
    __syncthreads();

    if (ATOMIC) {
        float* p = outp + (size_t)nh * PKS_;
#pragma unroll
        for (int r = 0; r < 4; ++r) {
            const int dd = (dt << 4) + (kg << 2) + r;   // D row = (lane>>4)*4+reg
            const int vv = (vt << 4) + row_l;           // D col = lane&15
            atomicAdd(&p[dd * D_ + vv], cacc[r]);
        }
        if (t < 32) {
            const float s = red_ks[0][t >> 2][t & 3] + red_ks[1][t >> 2][t & 3]
                          + red_ks[2][t >> 2][t & 3] + red_ks[3][t >> 2][t & 3];
            atomicAdd(&p[KVE_ + t], s);
        }
    } else {
        float* p = outp + ((size_t)nh * CH1_ + chunk) * PKS_;
#pragma unroll
        for (int r = 0; r < 4; ++r) {
            const int dd = (dt << 4) + (kg << 2) + r;
            const int vv = (vt << 4) + row_l;
            p[dd * D_ + vv] = cacc[r];
        }
        if (t < 32) {
            p[KVE_ + t] = red_ks[0][t >> 2][t & 3] + red_ks[1][t >> 2][t & 3]
                        + red_ks[2][t >> 2][t & 3] + red_ks[3][t >> 2][t & 3];
        }
    }
}

// ---- Phase 1b: deterministic 16-way reduce + split-bf16 transpose ----
__global__ __launch_bounds__(256) void la_reduce(
    const float* __restrict__ partials,
    short* __restrict__ kvThi, short* __restrict__ kvTlo,
    float* __restrict__ ksumf)
{
    const int nh = blockIdx.x;
    for (int e = threadIdx.x; e < PKS_; e += 256) {
        const float* p = partials + (size_t)nh * CH1_ * PKS_ + e;
        float s = 0.f;
#pragma unroll
        for (int c = 0; c < CH1_; ++c) s += p[(size_t)c * PKS_];
        if (e < KVE_) {
            const int d = e >> 5, v = e & 31;
            short hi, lo; split_bf16(s, hi, lo);
            kvThi[nh * KVE_ + v * D_ + d] = hi;
            kvTlo[nh * KVE_ + v * D_ + d] = lo;
        } else {
            ksumf[nh * D_ + (e - KVE_)] = s;
        }
    }
}

// atomic-path variant: same split/transpose from a finished kvf buffer
__global__ __launch_bounds__(256) void la_convert(
    const float* __restrict__ kvf,
    short* __restrict__ kvThi, short* __restrict__ kvTlo,
    float* __restrict__ ksumf)
{
    const int nh = blockIdx.x;
    for (int e = threadIdx.x; e < PKS_; e += 256) {
        const float s = kvf[(size_t)nh * PKS_ + e];
        if (e < KVE_) {
            const int d = e >> 5, v = e & 31;
            short hi, lo; split_bf16(s, hi, lo);
            kvThi[nh * KVE_ + v * D_ + d] = hi;
            kvTlo[nh * KVE_ + v * D_ + d] = lo;
        } else {
            ksumf[nh * D_ + (e - KVE_)] = s;
        }
    }
}

__global__ void la_zero(float* __restrict__ p, int nelem) {
    const int i = blockIdx.x * 256 + threadIdx.x;
    if (i < nelem) p[i] = 0.f;
}

// ------- Phase 2: MFMA split-bf16, 2 tiles/wave, dense NT f32x4 stores ------
// Block = 512 threads (8 waves) x 32 rows x ALL 8 h. All 4 Q loads issued
// pre-barrier (one latency exposure); B+Ksum loaded once, used for 2 tiles.
// mfma(KV_frag, phiQ_frag): lane holds out[l][v=kg*4+r] dense. 4 NT f32x4
// stores/thread. LDS 32KB -> 4 blocks/CU (occupancy unchanged).
__global__ __launch_bounds__(512) void la_phase2(
    const float* __restrict__ queries,
    const short* __restrict__ kvThi, const short* __restrict__ kvTlo,
    const float* __restrict__ ksumf, float* __restrict__ out)
{
    __shared__ float qs[32 * 256];              // 32 KB, swizzled granules
    const int t = threadIdx.x, lane = t & 63, w = t >> 6;
    const size_t rowg0 = (size_t)blockIdx.x * 32;
    const int n  = (int)(rowg0 >> 13);
    const int h  = w;                           // wave's head
    const int nh = n * 8 + h;
    const int row_l = lane & 15;                // frag row within tile
    const int kg    = lane >> 4;                // k-group: k = kg*8 + e

    // ---- stage 32 rows x 1KB: thread (row=t&15, seg=t>>4) loads 2x32B ----
    // (rows row and row+16 share row&7 -> same swizzle; all loads in flight)
    {
        const int row = t & 15, seg = t >> 4;   // seg 0..31
        const float* qp0 = queries + (rowg0 + row) * 256 + seg * 8;
        const float* qp1 = qp0 + 16 * 256;
        const float4 a0 = *(const float4*)(qp0);
        const float4 b0 = *(const float4*)(qp0 + 4);
        const float4 a1 = *(const float4*)(qp1);
        const float4 b1 = *(const float4*)(qp1 + 4);
        const int p0 = ((seg << 1) | 0) ^ (row & 7);
        const int p1 = ((seg << 1) | 1) ^ (row & 7);
        *(float4*)&qs[row * 256 + p0 * 4] =
            make_float4(phi_f(a0.x), phi_f(a0.y), phi_f(a0.z), phi_f(a0.w));
        *(float4*)&qs[row * 256 + p1 * 4] =
            make_float4(phi_f(b0.x), phi_f(b0.y), phi_f(b0.z), phi_f(b0.w));
        *(float4*)&qs[(row + 16) * 256 + p0 * 4] =
            make_float4(phi_f(a1.x), phi_f(a1.y), phi_f(a1.z), phi_f(a1.w));
        *(float4*)&qs[(row + 16) * 256 + p1 * 4] =
            make_float4(phi_f(b1.x), phi_f(b1.y), phi_f(b1.z), phi_f(b1.w));
    }

    // ---- KV + Ksum for this wave's h, loaded ONCE (L2-hot) ----
    const short* bh = kvThi + (size_t)nh * KVE_;
    const short* bl = kvTlo + (size_t)nh * KVE_;
    const short8 bh0 = *(const short8*)(bh + (row_l     ) * D_ + kg * 8);
    const short8 bh1 = *(const short8*)(bh + (row_l + 16) * D_ + kg * 8);
    const short8 bl0 = *(const short8*)(bl + (row_l     ) * D_ + kg * 8);
    const short8 bl1 = *(const short8*)(bl + (row_l + 16) * D_ + kg * 8);
    const float4 kA = *(const float4*)(ksumf + nh * D_ + kg * 8);
    const float4 kB = *(const float4*)(ksumf + nh * D_ + kg * 8 + 4);

    __syncthreads();

#pragma unroll
    for (int tt = 0; tt < 2; ++tt) {
        const int rl = row_l + tt * 16;         // LDS row (swizzle: rl&7 = row_l&7)

        // ---- phiQ[rl][kg*8..+8] from LDS (granules h*8+kg*2, +1) ----
        float qa[8];
        {
            const int g0 = (h * 8 + kg * 2)     ^ (row_l & 7);
            const int g1 = (h * 8 + kg * 2 + 1) ^ (row_l & 7);
            const float4 f0 = *(const float4*)&qs[rl * 256 + g0 * 4];
            const float4 f1 = *(const float4*)&qs[rl * 256 + g1 * 4];
            qa[0] = f0.x; qa[1] = f0.y; qa[2] = f0.z; qa[3] = f0.w;
            qa[4] = f1.x; qa[5] = f1.y; qa[6] = f1.z; qa[7] = f1.w;
        }
        short8 ahi, alo;
#pragma unroll
        for (int e = 0; e < 8; ++e) {
            short hs, ls; split_bf16(qa[e], hs, ls);
            ahi[e] = hs; alo[e] = ls;
        }

        // ---- 6 MFMAs, swapped operands (D transposed): lane -> dense f32x4 ----
        f32x4 c0 = {0.f, 0.f, 0.f, 0.f}, c1 = {0.f, 0.f, 0.f, 0.f};
        c0 = __builtin_amdgcn_mfma_f32_16x16x32_bf16(bh0, alo, c0, 0, 0, 0);
        c0 = __builtin_amdgcn_mfma_f32_16x16x32_bf16(bl0, ahi, c0, 0, 0, 0);
        c0 = __builtin_amdgcn_mfma_f32_16x16x32_bf16(bh0, ahi, c0, 0, 0, 0);
        c1 = __builtin_amdgcn_mfma_f32_16x16x32_bf16(bh1, alo, c1, 0, 0, 0);
        c1 = __builtin_amdgcn_mfma_f32_16x16x32_bf16(bl1, ahi, c1, 0, 0, 0);
        c1 = __builtin_amdgcn_mfma_f32_16x16x32_bf16(bh1, ahi, c1, 0, 0, 0);

        // ---- dot = phiQ . Ksum in fp32; reduce the 4 k-groups per row ----
        float dt = qa[0] * kA.x;
        dt = fmaf(qa[1], kA.y, dt); dt = fmaf(qa[2], kA.z, dt);
        dt = fmaf(qa[3], kA.w, dt); dt = fmaf(qa[4], kB.x, dt);
        dt = fmaf(qa[5], kB.y, dt); dt = fmaf(qa[6], kB.z, dt);
        dt = fmaf(qa[7], kB.w, dt);
        dt += __shfl_xor(dt, 16);
        dt += __shfl_xor(dt, 32);               // all lanes hold own row's dot

        // ---- normalize + dense NT f32x4 stores ----
        const float z = __builtin_amdgcn_rcpf(dt + 1e-6f);
        float* ob = out + (rowg0 + rl) * 256 + h * D_;
        const f32x4 o0 = {c0[0] * z, c0[1] * z, c0[2] * z, c0[3] * z};
        const f32x4 o1 = {c1[0] * z, c1[1] * z, c1[2] * z, c1[3] * z};
        __builtin_nontemporal_store(o0, (f32x4*)(ob + kg * 4));
        __builtin_nontemporal_store(o1, (f32x4*)(ob + 16 + kg * 4));
    }
}

extern "C" void kernel_launch(void* const* d_in, const int* in_sizes, int n_in,
                              void* d_out, int out_size, void* d_ws, size_t ws_size,
                              hipStream_t stream)
{
    const float* queries = (const float*)d_in[0];
    const float* keys    = (const float*)d_in[1];
    const float* values  = (const float*)d_in[2];
    float* out = (float*)d_out;
    float* ws  = (float*)d_ws;

    const size_t partial_elems = (size_t)NH_ * CH1_ * PKS_;    // 1,081,344 floats
    const size_t split_elems   = (size_t)NH_ * KVE_;           // per hi/lo, in shorts
    const size_t split_floats  = split_elems / 2;              // 32,768 float-slots each
    const size_t ksum_floats   = (size_t)NH_ * D_;             // 2,048
    const dim3 blk(256);
    const dim3 blk2(512);
    const int p2_blocks = (N_ * L_) / 32;                      // 2048

    if (ws_size >= (partial_elems + 2 * split_floats + ksum_floats) * sizeof(float)) {
        // deterministic two-stage reduction + split-bf16 conversion
        float* partials = ws;
        short* kvThi = (short*)(ws + partial_elems);
        short* kvTlo = kvThi + split_elems;
        float* ksumf = (float*)(kvTlo + split_elems);
        la_phase1<false><<<dim3(NH_, CH1_), blk, 0, stream>>>(keys, values, partials);
        la_reduce<<<dim3(NH_), blk, 0, stream>>>(partials, kvThi, kvTlo, ksumf);
        la_phase2<<<dim3(p2_blocks), blk2, 0, stream>>>(queries, kvThi, kvTlo, ksumf, out);
    } else {
        // fallback: atomic accumulation into zeroed kvf, then convert
        float* kvf = ws;
        short* kvThi = (short*)(ws + (size_t)NH_ * PKS_);
        short* kvTlo = kvThi + split_elems;
        float* ksumf = (float*)(kvTlo + split_elems);
        const int nz = (int)((size_t)NH_ * PKS_);
        la_zero<<<dim3((nz + 255) / 256), blk, 0, stream>>>(kvf, nz);
        la_phase1<true><<<dim3(NH_, CH1_), blk, 0, stream>>>(keys, values, kvf);
        la_convert<<<dim3(NH_), blk, 0, stream>>>(kvf, kvThi, kvTlo, ksumf);
        la_phase2<<<dim3(p2_blocks), blk2, 0, stream>>>(queries, kvThi, kvTlo, ksumf, out);
    }
}

// Round 23
// 56.610 us; speedup vs baseline: 1.0241x; 1.0133x over previous
//
#include <hip/hip_runtime.h>
#include <hip/hip_bf16.h>

// Linear attention, fp32. N=8, L=S=8192, H=8, D=Dv=32.
// out[n,l,h,v] = (sum_d phiQ[l,d]*KV[d][v]) * 1/(sum_d phiQ[l,d]*Ksum[d] + 1e-6)
// where KV[d][v] = sum_s phiK[s,d]*values[s,v]  (the /S and *S of the reference
// cancel exactly: S is a power of two).
//
// R23: last untested phase2 cell -- R14's barrier-free one-shot structure
// (32K waves, direct per-lane Q reads, no LDS) combined with the two
// accumulated wins: swapped-operand MFMA (lane holds out[row][v-quad] ->
// dense f32x4, verified R21) and NT stores (cache-pollution fix, R19).
// All barrier-staged variants (R19/R21/R22) pin p2 at ~35us; this removes
// the block-convergence + LDS round-trip from the critical chain.
// Phase1 = R14 (MFMA, at floor 20.7us measured R16). If null -> roofline.

#define N_      8
#define L_      8192
#define S_      8192
#define H_      8
#define D_      32
#define NH_     64            // N*H
#define CH1_    16            // phase-1 s-chunks per (n,h)
#define SPC1_   512           // s per phase-1 block
#define STR1_   36            // u32 row stride (144B: 16B-aligned, shift 4)
#define KVE_    (D_ * D_)     // 1024
#define PKS_    (KVE_ + D_)   // 1056 floats: KV + Ksum

typedef short short8 __attribute__((ext_vector_type(8)));
typedef float f32x4  __attribute__((ext_vector_type(4)));

__device__ __forceinline__ float phi_f(float x) {
    // elu(x)+1 : x>0 -> x+1 ; else exp(x)
    return x > 0.f ? x + 1.f : __expf(x);
}

__device__ __forceinline__ unsigned short bf16_bits(float x) {
    __hip_bfloat16 h = __float2bfloat16(x);   // RNE
    unsigned short u;
    __builtin_memcpy(&u, &h, 2);
    return u;
}

__device__ __forceinline__ void split_bf16(float x, short& hi, short& lo) {
    __hip_bfloat16 hb = __float2bfloat16(x);        // RNE
    const float xh = __bfloat162float(hb);
    __hip_bfloat16 lb = __float2bfloat16(x - xh);
    __builtin_memcpy(&hi, &hb, 2);
    __builtin_memcpy(&lo, &lb, 2);
}

// ---------------- Phase 1: C[32d x 32v] = phiK^T . V per (n,h,chunk) --------
// (R14 version: MFMA, single-bf16 K/V, exact fp32 Ksum, g^=row>>3 swizzle.)
template <bool ATOMIC>
__global__ __launch_bounds__(256) void la_phase1(
    const float* __restrict__ keys, const float* __restrict__ values,
    float* __restrict__ outp /* ATOMIC ? kvfinal[NH][PKS] : partials[NH][CH1][PKS] */)
{
    __shared__ unsigned kS[2][32][STR1_];
    __shared__ unsigned vS[2][32][STR1_];
    __shared__ float red_ks[4][8][4];
    const int nh = blockIdx.x, chunk = blockIdx.y;
    const int n = nh >> 3, h = nh & 7;
    const int t = threadIdx.x, lane = t & 63, w = t >> 6;
    const int row8 = t >> 3;           // 0..31 (s-row within tile half)
    const int c4   = t & 7;            // float4 column (4 d's / 4 v's)
    const int row_l = lane & 15, kg = lane >> 4;
    const int dt = w >> 1, vt = w & 1; // wave's C-tile
    const int odd = row8 & 1;
    const int dv0 = (c4 << 2) + (odd ? 2 : 0);   // first of 2 owned d-rows
    const int s2lo = row8 >> 1;                  // u32 s-pair index (lo half)
    const float* kb = keys   + ((size_t)n * S_) * 256 + h * 32 + (c4 << 2);
    const float* vb = values + ((size_t)n * S_) * 256 + h * 32 + (c4 << 2);
    const int s0 = chunk * SPC1_;

    float ks4[4] = {0.f, 0.f, 0.f, 0.f};
    f32x4 cacc = {0.f, 0.f, 0.f, 0.f};
    float4 Lka, Lkb, Lva, Lvb;

    auto LOADT = [&](int tb) {
        const size_t g0 = ((size_t)(s0 + (tb << 6) + row8)) << 8;
        const size_t g1 = ((size_t)(s0 + (tb << 6) + row8 + 32)) << 8;
        Lka = *(const float4*)(kb + g0);
        Lkb = *(const float4*)(kb + g1);
        Lva = *(const float4*)(vb + g0);
        Lvb = *(const float4*)(vb + g1);
    };
    auto STORE4 = [&](unsigned (*Sarr)[STR1_], const unsigned short* x, int s2) {
        const unsigned mA = (unsigned)x[0] | ((unsigned)x[1] << 16);
        const unsigned mB = (unsigned)x[2] | ((unsigned)x[3] << 16);
        const unsigned pA = __shfl_xor(mA, 8);
        const unsigned pB = __shfl_xor(mB, 8);
        const unsigned m = odd ? mB : mA, p = odd ? pB : pA;
        const unsigned se = odd ? p : m;          // s-even's two bf16 (j, j+1)
        const unsigned so = odd ? m : p;          // s-odd's
        const unsigned w0 = (se & 0xffffu) | ((so & 0xffffu) << 16);
        const unsigned w1 = (se >> 16) | (so & 0xffff0000u);
        Sarr[dv0][4 * ((s2 >> 2) ^ (dv0 >> 3)) + (s2 & 3)]           = w0;
        Sarr[dv0 + 1][4 * ((s2 >> 2) ^ ((dv0 + 1) >> 3)) + (s2 & 3)] = w1;
    };
    auto PROCT = [&](int buf) {
        const float f0[4] = {phi_f(Lka.x), phi_f(Lka.y), phi_f(Lka.z), phi_f(Lka.w)};
        const float f1[4] = {phi_f(Lkb.x), phi_f(Lkb.y), phi_f(Lkb.z), phi_f(Lkb.w)};
        unsigned short kx[4], ky[4], vx[4], vy[4];
#pragma unroll
        for (int j = 0; j < 4; ++j) ks4[j] += f0[j] + f1[j];
        kx[0] = bf16_bits(f0[0]); kx[1] = bf16_bits(f0[1]);
        kx[2] = bf16_bits(f0[2]); kx[3] = bf16_bits(f0[3]);
        ky[0] = bf16_bits(f1[0]); ky[1] = bf16_bits(f1[1]);
        ky[2] = bf16_bits(f1[2]); ky[3] = bf16_bits(f1[3]);
        vx[0] = bf16_bits(Lva.x); vx[1] = bf16_bits(Lva.y);
        vx[2] = bf16_bits(Lva.z); vx[3] = bf16_bits(Lva.w);
        vy[0] = bf16_bits(Lvb.x); vy[1] = bf16_bits(Lvb.y);
        vy[2] = bf16_bits(Lvb.z); vy[3] = bf16_bits(Lvb.w);
        STORE4(kS[buf], kx, s2lo);
        STORE4(kS[buf], ky, s2lo + 16);
        STORE4(vS[buf], vx, s2lo);
        STORE4(vS[buf], vy, s2lo + 16);
    };
    auto FRAG = [&](const unsigned (*Sarr)[STR1_], int row, int sh) -> short8 {
        const int g = ((sh << 2) | kg) ^ (row >> 3);
        union { uint4 u; short8 s; } U;
        U.u = *(const uint4*)&Sarr[row][g << 2];
        return U.s;
    };
    auto COMPT = [&](int buf) {
#pragma unroll
        for (int sh = 0; sh < 2; ++sh) {
            const short8 A = FRAG(kS[buf], (dt << 4) + row_l, sh);
            const short8 B = FRAG(vS[buf], (vt << 4) + row_l, sh);
            cacc = __builtin_amdgcn_mfma_f32_16x16x32_bf16(A, B, cacc, 0, 0, 0);
        }
    };

    LOADT(0);
    PROCT(0);
    __syncthreads();
#pragma unroll
    for (int tb = 0; tb < 8; ++tb) {
        const int cur = tb & 1;
        if (tb < 7) LOADT(tb + 1);       // next-tile loads in flight (T14)
        COMPT(cur);
        if (tb < 7) PROCT(cur ^ 1);      // waits vmcnt, stages other buffer
        __syncthreads();
    }

    // ksum: butterfly over lane bits 3..5 (8 same-c4 lanes), then cross-wave
#pragma unroll
    for (int j = 0; j < 4; ++j) {
        float x = ks4[j];
        x += __shfl_xor(x, 8);
        x += __shfl_xor(x, 16);
        x += __shfl_xor(x, 32);
        ks4[j] = x;
    }
    if (lane < 8) {
#pragma unroll
        for (int j = 0; j < 4; ++j) red_ks[w][lane][j] = ks4[j];
    }
    __syncthreads();

    if (ATOMIC) {
        float* p = outp + (size_t)nh * PKS_;
#pragma unroll
        for (int r = 0; r < 4; ++r) {
            const int dd = (dt << 4) + (kg << 2) + r;   // D row = (lane>>4)*4+reg
            const int vv = (vt << 4) + row_l;           // D col = lane&15
            atomicAdd(&p[dd * D_ + vv], cacc[r]);
        }
        if (t < 32) {
            const float s = red_ks[0][t >> 2][t & 3] + red_ks[1][t >> 2][t & 3]
                          + red_ks[2][t >> 2][t & 3] + red_ks[3][t >> 2][t & 3];
            atomicAdd(&p[KVE_ + t], s);
        }
    } else {
        float* p = outp + ((size_t)nh * CH1_ + chunk) * PKS_;
#pragma unroll
        for (int r = 0; r < 4; ++r) {
            const int dd = (dt << 4) + (kg << 2) + r;
            const int vv = (vt << 4) + row_l;
            p[dd * D_ + vv] = cacc[r];
        }
        if (t < 32) {
            p[KVE_ + t] = red_ks[0][t >> 2][t & 3] + red_ks[1][t >> 2][t & 3]
                        + red_ks[2][t >> 2][t & 3] + red_ks[3][t >> 2][t & 3];
        }
    }
}

// ---- Phase 1b: deterministic 16-way reduce + split-bf16 transpose ----
__global__ __launch_bounds__(256) void la_reduce(
    const float* __restrict__ partials,
    short* __restrict__ kvThi, short* __restrict__ kvTlo,
    float* __restrict__ ksumf)
{
    const int nh = blockIdx.x;
    for (int e = threadIdx.x; e < PKS_; e += 256) {
        const float* p = partials + (size_t)nh * CH1_ * PKS_ + e;
        float s = 0.f;
#pragma unroll
        for (int c = 0; c < CH1_; ++c) s += p[(size_t)c * PKS_];
        if (e < KVE_) {
            const int d = e >> 5, v = e & 31;
            short hi, lo; split_bf16(s, hi, lo);
            kvThi[nh * KVE_ + v * D_ + d] = hi;
            kvTlo[nh * KVE_ + v * D_ + d] = lo;
        } else {
            ksumf[nh * D_ + (e - KVE_)] = s;
        }
    }
}

// atomic-path variant: same split/transpose from a finished kvf buffer
__global__ __launch_bounds__(256) void la_convert(
    const float* __restrict__ kvf,
    short* __restrict__ kvThi, short* __restrict__ kvTlo,
    float* __restrict__ ksumf)
{
    const int nh = blockIdx.x;
    for (int e = threadIdx.x; e < PKS_; e += 256) {
        const float s = kvf[(size_t)nh * PKS_ + e];
        if (e < KVE_) {
            const int d = e >> 5, v = e & 31;
            short hi, lo; split_bf16(s, hi, lo);
            kvThi[nh * KVE_ + v * D_ + d] = hi;
            kvTlo[nh * KVE_ + v * D_ + d] = lo;
        } else {
            ksumf[nh * D_ + (e - KVE_)] = s;
        }
    }
}

__global__ void la_zero(float* __restrict__ p, int nelem) {
    const int i = blockIdx.x * 256 + threadIdx.x;
    if (i < nelem) p[i] = 0.f;
}

// -- Phase 2: barrier-free one-shot (R14 structure) + transposed D + NT -----
// Wave-task = (16-row tile, h); 32768 waves. Direct per-lane Q reads (no
// LDS, no barrier). mfma(KV_frag, phiQ_frag): lane holds out[l=row_l]
// [v=kg*4+r] -> dense f32x4; 2 NT f32x4 stores/thread; single rcp.
__global__ __launch_bounds__(256) void la_phase2(
    const float* __restrict__ queries,
    const short* __restrict__ kvThi, const short* __restrict__ kvTlo,
    const float* __restrict__ ksumf, float* __restrict__ out)
{
    const int t = threadIdx.x, lane = t & 63, w = t >> 6;
    const int wt = blockIdx.x * 4 + w;      // 0..32767
    const int h  = wt & 7;
    const int rt = wt >> 3;                 // 16-row tile id, 0..4095
    const size_t rowg0 = (size_t)rt * 16;   // global (n,l)-row base
    const int n = (int)(rowg0 >> 13);
    const int nh = n * 8 + h;
    const int row_l = lane & 15;            // Q-row (frag row)
    const int kg    = lane >> 4;            // k-group: k = kg*8 + e

    // ---- phiQ frag: direct per-lane loads, kept fp32 for dot ----
    const float* qp = queries + (rowg0 + row_l) * 256 + h * D_ + kg * 8;
    float qa[8];
    {
        const float4 qA = *(const float4*)(qp);
        const float4 qB = *(const float4*)(qp + 4);
        qa[0] = phi_f(qA.x); qa[1] = phi_f(qA.y); qa[2] = phi_f(qA.z); qa[3] = phi_f(qA.w);
        qa[4] = phi_f(qB.x); qa[5] = phi_f(qB.y); qa[6] = phi_f(qB.z); qa[7] = phi_f(qB.w);
    }
    short8 ahi, alo;
#pragma unroll
    for (int e = 0; e < 8; ++e) {
        short hs, ls; split_bf16(qa[e], hs, ls);
        ahi[e] = hs; alo[e] = ls;
    }

    // ---- KV frags + Ksum (L2/L3-hot) ----
    const short* bh = kvThi + (size_t)nh * KVE_;
    const short* bl = kvTlo + (size_t)nh * KVE_;
    const short8 bh0 = *(const short8*)(bh + (row_l     ) * D_ + kg * 8);
    const short8 bh1 = *(const short8*)(bh + (row_l + 16) * D_ + kg * 8);
    const short8 bl0 = *(const short8*)(bl + (row_l     ) * D_ + kg * 8);
    const short8 bl1 = *(const short8*)(bl + (row_l + 16) * D_ + kg * 8);
    const float4 kA = *(const float4*)(ksumf + nh * D_ + kg * 8);
    const float4 kB = *(const float4*)(ksumf + nh * D_ + kg * 8 + 4);

    // ---- 6 MFMAs, swapped operands (D transposed): lane -> dense f32x4 ----
    f32x4 c0 = {0.f, 0.f, 0.f, 0.f}, c1 = {0.f, 0.f, 0.f, 0.f};
    c0 = __builtin_amdgcn_mfma_f32_16x16x32_bf16(bh0, alo, c0, 0, 0, 0);
    c0 = __builtin_amdgcn_mfma_f32_16x16x32_bf16(bl0, ahi, c0, 0, 0, 0);
    c0 = __builtin_amdgcn_mfma_f32_16x16x32_bf16(bh0, ahi, c0, 0, 0, 0);
    c1 = __builtin_amdgcn_mfma_f32_16x16x32_bf16(bh1, alo, c1, 0, 0, 0);
    c1 = __builtin_amdgcn_mfma_f32_16x16x32_bf16(bl1, ahi, c1, 0, 0, 0);
    c1 = __builtin_amdgcn_mfma_f32_16x16x32_bf16(bh1, ahi, c1, 0, 0, 0);

    // ---- dot = phiQ . Ksum in fp32; reduce the 4 k-groups per row ----
    float dt = qa[0] * kA.x;
    dt = fmaf(qa[1], kA.y, dt); dt = fmaf(qa[2], kA.z, dt);
    dt = fmaf(qa[3], kA.w, dt); dt = fmaf(qa[4], kB.x, dt);
    dt = fmaf(qa[5], kB.y, dt); dt = fmaf(qa[6], kB.z, dt);
    dt = fmaf(qa[7], kB.w, dt);
    dt += __shfl_xor(dt, 16);
    dt += __shfl_xor(dt, 32);   // all lanes hold dot[row_l] = own row's dot

    // ---- normalize + dense NT f32x4 stores ----
    const float z = __builtin_amdgcn_rcpf(dt + 1e-6f);
    float* ob = out + (rowg0 + row_l) * 256 + h * D_;
    const f32x4 o0 = {c0[0] * z, c0[1] * z, c0[2] * z, c0[3] * z};
    const f32x4 o1 = {c1[0] * z, c1[1] * z, c1[2] * z, c1[3] * z};
    __builtin_nontemporal_store(o0, (f32x4*)(ob + kg * 4));
    __builtin_nontemporal_store(o1, (f32x4*)(ob + 16 + kg * 4));
}

extern "C" void kernel_launch(void* const* d_in, const int* in_sizes, int n_in,
                              void* d_out, int out_size, void* d_ws, size_t ws_size,
                              hipStream_t stream)
{
    const float* queries = (const float*)d_in[0];
    const float* keys    = (const float*)d_in[1];
    const float* values  = (const float*)d_in[2];
    float* out = (float*)d_out;
    float* ws  = (float*)d_ws;

    const size_t partial_elems = (size_t)NH_ * CH1_ * PKS_;    // 1,081,344 floats
    const size_t split_elems   = (size_t)NH_ * KVE_;           // per hi/lo, in shorts
    const size_t split_floats  = split_elems / 2;              // 32,768 float-slots each
    const size_t ksum_floats   = (size_t)NH_ * D_;             // 2,048
    const dim3 blk(256);
    const int p2_blocks = (N_ * L_ * H_) / 16 / 4;             // 8192

    if (ws_size >= (partial_elems + 2 * split_floats + ksum_floats) * sizeof(float)) {
        // deterministic two-stage reduction + split-bf16 conversion
        float* partials = ws;
        short* kvThi = (short*)(ws + partial_elems);
        short* kvTlo = kvThi + split_elems;
        float* ksumf = (float*)(kvTlo + split_elems);
        la_phase1<false><<<dim3(NH_, CH1_), blk, 0, stream>>>(keys, values, partials);
        la_reduce<<<dim3(NH_), blk, 0, stream>>>(partials, kvThi, kvTlo, ksumf);
        la_phase2<<<dim3(p2_blocks), blk, 0, stream>>>(queries, kvThi, kvTlo, ksumf, out);
    } else {
        // fallback: atomic accumulation into zeroed kvf, then convert
        float* kvf = ws;
        short* kvThi = (short*)(ws + (size_t)NH_ * PKS_);
        short* kvTlo = kvThi + split_elems;
        float* ksumf = (float*)(kvTlo + split_elems);
        const int nz = (int)((size_t)NH_ * PKS_);
        la_zero<<<dim3((nz + 255) / 256), blk, 0, stream>>>(kvf, nz);
        la_phase1<true><<<dim3(NH_, CH1_), blk, 0, stream>>>(keys, values, kvf);
        la_convert<<<dim3(NH_), blk, 0, stream>>>(kvf, kvThi, kvTlo, ksumf);
        la_phase2<<<dim3(p2_blocks), blk, 0, stream>>>(queries, kvThi, kvTlo, ksumf, out);
    }
}